// Round 1
// baseline (36.639 us; speedup 1.0000x reference)
//
#include <hip/hip_runtime.h>

#define IN_SIZE 11
#define HID 16
#define FEAT 18
#define TSTEPS 18

__device__ __forceinline__ float fast_rcp(float v) { return __builtin_amdgcn_rcpf(v); }

__device__ __forceinline__ float fsigmoid(float v) {
    // robust: exp(-v) -> inf gives 0, -> 0 gives 1
    return fast_rcp(1.0f + __expf(-v));
}

__device__ __forceinline__ float ftanh(float v) {
    v = fminf(fmaxf(v, -15.0f), 15.0f);   // saturates anyway; avoids inf/inf
    const float e = __expf(2.0f * v);
    return (e - 1.0f) * fast_rcp(e + 1.0f);
}

// One graph per 16 lanes. Lane u owns hidden unit u (gate rows u, 16+u, 32+u, 48+u).
// Only the first min(cnt, 18) edges of each graph contribute (reference's
// truncation semantics via scatter mode='drop' into a [B,18,18] seq buffer).
extern "C" __global__ __launch_bounds__(256, 1)
void tgnn_lstm_fused(const float* __restrict__ x,
                     const float* __restrict__ W_ih,
                     const float* __restrict__ W_hh,
                     const float* __restrict__ b_ih,
                     const float* __restrict__ b_hh,
                     const float* __restrict__ W_fc,
                     const float* __restrict__ b_fc,
                     const int* __restrict__ edge_index,
                     const int* __restrict__ edge_attr,
                     const int* __restrict__ batch,
                     float* __restrict__ out,
                     int E, int B)
{
    const int tid = blockIdx.x * blockDim.x + threadIdx.x;
    const int g = tid >> 4;
    const int u = tid & 15;
    if (g >= B) return;

    // ---- lower_bound(batch, g) on lane 0, lower_bound(batch, g+1) on lane 1 ----
    int res = E;
    if (u < 2) {
        const int target = g + u;
        int lo = 0, hi = E;
        while (lo < hi) {
            const int mid = (lo + hi) >> 1;
            if (batch[mid] < target) lo = mid + 1; else hi = mid;
        }
        res = lo;
    }
    const int first_g = __shfl(res, 0, 16);
    const int cnt = __shfl(res, 1, 16) - first_g;   // #edges in graph g

    // ---- per-lane weight rows in registers (all indices compile-time) ----
    float wih[4][FEAT];
    float whh[4][HID];
    float bias[4];
#pragma unroll
    for (int r = 0; r < 4; ++r) {
        const int row = r * HID + u;
#pragma unroll
        for (int k = 0; k < FEAT; ++k) wih[r][k] = W_ih[row * FEAT + k];
#pragma unroll
        for (int v = 0; v < HID; ++v) whh[r][v] = W_hh[row * HID + v];
        bias[r] = b_ih[row] + b_hh[row];
    }

    // ---- LSTM over 18 timesteps ----
    float h = 0.0f, c = 0.0f;
    for (int t = 0; t < TSTEPS; ++t) {
        // this lane's share of x_t: lane u holds feature k=u (and k=u+16 for u<2)
        float v0 = 0.0f, v1 = 0.0f;
        if (t < cnt) {                       // uniform across the 16-lane group
            const int j = first_g + t;
            const int ea = edge_attr[j];
            if (u < IN_SIZE) {
                const int n1 = edge_index[j];
                const int n2 = edge_index[E + j];
                v0 = x[n1 * IN_SIZE + u] + x[n2 * IN_SIZE + u];
            } else {
                v0 = (ea == u - IN_SIZE) ? 1.0f : 0.0f;   // one-hot slots 0..4
            }
            if (u < 2) v1 = (ea == u + 5) ? 1.0f : 0.0f;  // one-hot slots 5..6
        }

        float a0 = bias[0], a1 = bias[1], a2 = bias[2], a3 = bias[3];
#pragma unroll
        for (int k = 0; k < 16; ++k) {
            const float xk = __shfl(v0, k, 16);
            a0 = fmaf(xk, wih[0][k], a0);
            a1 = fmaf(xk, wih[1][k], a1);
            a2 = fmaf(xk, wih[2][k], a2);
            a3 = fmaf(xk, wih[3][k], a3);
        }
#pragma unroll
        for (int k = 0; k < 2; ++k) {
            const float xk = __shfl(v1, k, 16);
            a0 = fmaf(xk, wih[0][16 + k], a0);
            a1 = fmaf(xk, wih[1][16 + k], a1);
            a2 = fmaf(xk, wih[2][16 + k], a2);
            a3 = fmaf(xk, wih[3][16 + k], a3);
        }
#pragma unroll
        for (int v = 0; v < HID; ++v) {
            const float hv = __shfl(h, v, 16);
            a0 = fmaf(hv, whh[0][v], a0);
            a1 = fmaf(hv, whh[1][v], a1);
            a2 = fmaf(hv, whh[2][v], a2);
            a3 = fmaf(hv, whh[3][v], a3);
        }

        const float ig = fsigmoid(a0);
        const float fg = fsigmoid(a1);
        const float gg = ftanh(a2);
        const float og = fsigmoid(a3);
        c = fmaf(fg, c, ig * gg);
        h = og * ftanh(c);
    }

    // ---- fc: out[g] = h @ W_fc.T + b_fc (4 outputs) ----
    float p0 = h * W_fc[0 * HID + u];
    float p1 = h * W_fc[1 * HID + u];
    float p2 = h * W_fc[2 * HID + u];
    float p3 = h * W_fc[3 * HID + u];
#pragma unroll
    for (int m = 8; m >= 1; m >>= 1) {
        p0 += __shfl_xor(p0, m, 16);
        p1 += __shfl_xor(p1, m, 16);
        p2 += __shfl_xor(p2, m, 16);
        p3 += __shfl_xor(p3, m, 16);
    }
    if (u == 0) {
        float4 r;
        r.x = p0 + b_fc[0];
        r.y = p1 + b_fc[1];
        r.z = p2 + b_fc[2];
        r.w = p3 + b_fc[3];
        reinterpret_cast<float4*>(out)[g] = r;
    }
}

extern "C" void kernel_launch(void* const* d_in, const int* in_sizes, int n_in,
                              void* d_out, int out_size, void* d_ws, size_t ws_size,
                              hipStream_t stream) {
    const float* x     = (const float*)d_in[0];
    const float* W_ih  = (const float*)d_in[1];
    const float* W_hh  = (const float*)d_in[2];
    const float* b_ih  = (const float*)d_in[3];
    const float* b_hh  = (const float*)d_in[4];
    const float* W_fc  = (const float*)d_in[5];
    const float* b_fc  = (const float*)d_in[6];
    const int* edge_index = (const int*)d_in[7];
    const int* edge_attr  = (const int*)d_in[8];
    const int* batch      = (const int*)d_in[9];

    const int E = in_sizes[8];       // N_EDGES (edge_attr count)
    const int B = out_size / 4;      // N_GRAPHS (OUT_SIZE = 4)

    const int threads = B * 16;
    const int block = 256;
    const int grid = (threads + block - 1) / block;
    tgnn_lstm_fused<<<grid, block, 0, stream>>>(x, W_ih, W_hh, b_ih, b_hh,
                                                W_fc, b_fc,
                                                edge_index, edge_attr, batch,
                                                (float*)d_out, E, B);
}

// Round 2
// 28.323 us; speedup vs baseline: 1.2936x; 1.2936x over previous
//
#include <hip/hip_runtime.h>

#define IN_SIZE 11
#define HID 16
#define FEAT 18
#define TSTEPS 18

__device__ __forceinline__ float fast_rcp(float v) { return __builtin_amdgcn_rcpf(v); }

__device__ __forceinline__ float fsigmoid(float v) {
    return fast_rcp(1.0f + __expf(-v));
}

__device__ __forceinline__ float ftanh(float v) {
    v = fminf(fmaxf(v, -15.0f), 15.0f);
    const float e = __expf(2.0f * v);
    return (e - 1.0f) * fast_rcp(e + 1.0f);
}

// One graph per 16 lanes; one wave = 4 consecutive graphs.
// Phase 1: cooperative k-ary lower_bound (16-ary per group for first[g],
//          64-ary whole-wave for first[g0+4], interleaved -> ~6 latency rounds).
// Phase 2: fully-unrolled 2-round gather of the first <=18 edges into LDS.
// Phase 3: rolled LSTM, features via ds_read_b128, pipelined 1 step ahead.
extern "C" __global__ __launch_bounds__(256, 1)
void tgnn_lstm_fused(const float* __restrict__ x,
                     const float* __restrict__ W_ih,
                     const float* __restrict__ W_hh,
                     const float* __restrict__ b_ih,
                     const float* __restrict__ b_hh,
                     const float* __restrict__ W_fc,
                     const float* __restrict__ b_fc,
                     const int* __restrict__ edge_index,
                     const int* __restrict__ edge_attr,
                     const int* __restrict__ batch,
                     float* __restrict__ out,
                     int E, int B)
{
    __shared__ __align__(16) float feat[16][TSTEPS][20];   // padded row: 16B-aligned, bank-clean

    const int tid = blockIdx.x * blockDim.x + threadIdx.x;
    const int g   = tid >> 4;            // graph for this 16-lane group
    const int u   = tid & 15;            // lane within group
    const int wl  = threadIdx.x & 63;    // lane within wave
    const int q   = wl >> 4;             // group within wave (0..3)
    const int grp = threadIdx.x >> 4;    // group within block (0..15)
    const int g0  = g - q;               // first graph of this wave

    // ---------------- Phase 1: cooperative searches ----------------
    // search1 (per group, 16 lanes): lower_bound(batch, g)
    // search2 (whole wave, 64 lanes): lower_bound(batch, g0+4)
    const int tgt1 = g;
    const int tgt2 = g0 + 4;
    int lo1 = 0, hi1 = E;
    int lo2 = 0, hi2 = E;

    while (__any(((hi1 - lo1) > 15) | ((hi2 - lo2) > 63))) {
        const unsigned long long n1r = (unsigned long long)(hi1 - lo1);
        const unsigned long long n2r = (unsigned long long)(hi2 - lo2);
        int p1 = lo1 + (int)((n1r * (unsigned)u) >> 4);
        int p2 = lo2 + (int)((n2r * (unsigned)wl) >> 6);
        if (p1 >= E) p1 = E - 1;
        if (p2 >= E) p2 = E - 1;
        // both probes issued before either is consumed -> one latency round
        const int b1 = batch[p1];
        const int b2 = batch[p2];
        const bool lt1 = (n1r > 0) && (b1 < tgt1);
        const bool lt2 = (n2r > 0) && (b2 < tgt2);

        const unsigned long long bal1 = __ballot(lt1);
        const unsigned m1 = (unsigned)((bal1 >> (q << 4)) & 0xffffULL);
        const int c1 = __popc(m1);
        const int pl1 = __shfl(p1, (q << 4) + (c1 > 0 ? c1 - 1 : 0), 64);
        const int ph1 = __shfl(p1, (q << 4) + (c1 < 16 ? c1 : 0), 64);
        if (c1 > 0)  lo1 = pl1 + 1;
        if (c1 < 16) hi1 = ph1;

        const unsigned long long bal2 = __ballot(lt2);
        const int c2 = __popcll(bal2);
        const int pl2 = __shfl(p2, (c2 > 0 ? c2 - 1 : 0), 64);
        const int ph2 = __shfl(p2, (c2 < 64 ? c2 : 0), 64);
        if (c2 > 0)  lo2 = pl2 + 1;
        if (c2 < 64) hi2 = ph2;
    }
    // finals (one more shared latency round)
    {
        const int nf1 = hi1 - lo1;           // <= 15
        const int nf2 = hi2 - lo2;           // <= 63
        int pf1 = lo1 + ((u < nf1) ? u : 0);
        int pf2 = lo2 + ((wl < nf2) ? wl : 0);
        if (pf1 >= E) pf1 = E - 1;
        if (pf2 >= E) pf2 = E - 1;
        const int b1 = batch[pf1];
        const int b2 = batch[pf2];
        const bool lt1 = (u < nf1) && (b1 < tgt1);
        const bool lt2 = (wl < nf2) && (b2 < tgt2);
        const unsigned long long bal1 = __ballot(lt1);
        lo1 += __popc((unsigned)((bal1 >> (q << 4)) & 0xffffULL));
        const unsigned long long bal2 = __ballot(lt2);
        lo2 += __popcll(bal2);
    }
    const int first = lo1;                               // uniform within group
    const int endnb = __shfl(lo1, (((q + 1) & 3) << 4), 64);  // next group's first
    const int endg  = (q < 3) ? endnb : lo2;
    int cnt = endg - first;
    if (cnt > TSTEPS) cnt = TSTEPS;
    if (cnt < 0) cnt = 0;

    // ---------------- weights into registers (independent of gather) --------
    float wih[4][FEAT];
    float whh[4][HID];
    float bias[4];
#pragma unroll
    for (int r = 0; r < 4; ++r) {
        const int row = r * HID + u;
#pragma unroll
        for (int k = 0; k < FEAT; ++k) wih[r][k] = W_ih[row * FEAT + k];
#pragma unroll
        for (int v = 0; v < HID; ++v) whh[r][v] = W_hh[row * HID + v];
        bias[r] = b_ih[row] + b_hh[row];
    }

    // ---------------- Phase 2: gather prefetch (2 latency rounds) ----------
    int n1a[TSTEPS], n2a[TSTEPS], eaa[TSTEPS];
#pragma unroll
    for (int t = 0; t < TSTEPS; ++t) {
        const bool valid = t < cnt;
        const int j = valid ? (first + t) : 0;
        n1a[t] = edge_index[j];
        n2a[t] = edge_index[E + j];
        eaa[t] = edge_attr[j];
    }
    float* fb = &feat[grp][0][0];
#pragma unroll
    for (int t = 0; t < TSTEPS; ++t) {
        const bool valid = t < cnt;
        float val;
        if (u < IN_SIZE) {
            const float xv = x[n1a[t] * IN_SIZE + u] + x[n2a[t] * IN_SIZE + u];
            val = valid ? xv : 0.0f;
        } else {
            val = (valid && (eaa[t] == u - IN_SIZE)) ? 1.0f : 0.0f;  // one-hot 0..4
        }
        fb[t * 20 + u] = val;
        if (u < 2) {
            fb[t * 20 + 16 + u] = (valid && (eaa[t] == u + 5)) ? 1.0f : 0.0f; // one-hot 5..6
        }
    }

    // ---------------- Phase 3: LSTM, pipelined feature reads ----------------
    float h = 0.0f, c = 0.0f;
    const float4* f4p = reinterpret_cast<const float4*>(fb);
    float4 c0 = f4p[0], c1 = f4p[1], c2 = f4p[2], c3 = f4p[3], c4 = f4p[4];

    for (int t = 0; t < TSTEPS; ++t) {
        const float fv0  = c0.x, fv1  = c0.y, fv2  = c0.z, fv3  = c0.w;
        const float fv4  = c1.x, fv5  = c1.y, fv6  = c1.z, fv7  = c1.w;
        const float fv8  = c2.x, fv9  = c2.y, fv10 = c2.z, fv11 = c2.w;
        const float fv12 = c3.x, fv13 = c3.y, fv14 = c3.z, fv15 = c3.w;
        const float fv16 = c4.x, fv17 = c4.y;
        if (t < TSTEPS - 1) {   // prefetch next step's features
            const float4* np = f4p + (t + 1) * 5;
            c0 = np[0]; c1 = np[1]; c2 = np[2]; c3 = np[3]; c4 = np[4];
        }

        float a0 = bias[0], a1 = bias[1], a2 = bias[2], a3 = bias[3];
#define ACC(FV, K) \
        a0 = fmaf(FV, wih[0][K], a0); a1 = fmaf(FV, wih[1][K], a1); \
        a2 = fmaf(FV, wih[2][K], a2); a3 = fmaf(FV, wih[3][K], a3);
        ACC(fv0, 0)  ACC(fv1, 1)  ACC(fv2, 2)   ACC(fv3, 3)
        ACC(fv4, 4)  ACC(fv5, 5)  ACC(fv6, 6)   ACC(fv7, 7)
        ACC(fv8, 8)  ACC(fv9, 9)  ACC(fv10, 10) ACC(fv11, 11)
        ACC(fv12, 12) ACC(fv13, 13) ACC(fv14, 14) ACC(fv15, 15)
        ACC(fv16, 16) ACC(fv17, 17)
#undef ACC
#pragma unroll
        for (int v = 0; v < HID; ++v) {
            const float hv = __shfl(h, v, 16);
            a0 = fmaf(hv, whh[0][v], a0);
            a1 = fmaf(hv, whh[1][v], a1);
            a2 = fmaf(hv, whh[2][v], a2);
            a3 = fmaf(hv, whh[3][v], a3);
        }

        const float ig = fsigmoid(a0);
        const float fg = fsigmoid(a1);
        const float gg = ftanh(a2);
        const float og = fsigmoid(a3);
        c = fmaf(fg, c, ig * gg);
        h = og * ftanh(c);
    }

    // ---------------- fc epilogue ----------------
    float p0 = h * W_fc[0 * HID + u];
    float p1 = h * W_fc[1 * HID + u];
    float p2 = h * W_fc[2 * HID + u];
    float p3 = h * W_fc[3 * HID + u];
#pragma unroll
    for (int m = 8; m >= 1; m >>= 1) {
        p0 += __shfl_xor(p0, m, 16);
        p1 += __shfl_xor(p1, m, 16);
        p2 += __shfl_xor(p2, m, 16);
        p3 += __shfl_xor(p3, m, 16);
    }
    if (u == 0 && g < B) {
        float4 r;
        r.x = p0 + b_fc[0];
        r.y = p1 + b_fc[1];
        r.z = p2 + b_fc[2];
        r.w = p3 + b_fc[3];
        reinterpret_cast<float4*>(out)[g] = r;
    }
}

extern "C" void kernel_launch(void* const* d_in, const int* in_sizes, int n_in,
                              void* d_out, int out_size, void* d_ws, size_t ws_size,
                              hipStream_t stream) {
    const float* x     = (const float*)d_in[0];
    const float* W_ih  = (const float*)d_in[1];
    const float* W_hh  = (const float*)d_in[2];
    const float* b_ih  = (const float*)d_in[3];
    const float* b_hh  = (const float*)d_in[4];
    const float* W_fc  = (const float*)d_in[5];
    const float* b_fc  = (const float*)d_in[6];
    const int* edge_index = (const int*)d_in[7];
    const int* edge_attr  = (const int*)d_in[8];
    const int* batch      = (const int*)d_in[9];

    const int E = in_sizes[8];       // N_EDGES
    const int B = out_size / 4;      // N_GRAPHS

    const int threads = B * 16;
    const int block = 256;
    const int grid = (threads + block - 1) / block;
    tgnn_lstm_fused<<<grid, block, 0, stream>>>(x, W_ih, W_hh, b_ih, b_hh,
                                                W_fc, b_fc,
                                                edge_index, edge_attr, batch,
                                                (float*)d_out, E, B);
}

// Round 3
// 27.862 us; speedup vs baseline: 1.3150x; 1.0165x over previous
//
#include <hip/hip_runtime.h>

#define IN_SIZE 11
#define HID 16
#define FEAT 18
#define TSTEPS 18

__device__ __forceinline__ float fast_rcp(float v) { return __builtin_amdgcn_rcpf(v); }
__device__ __forceinline__ float fsigmoid(float v) { return fast_rcp(1.0f + __expf(-v)); }
__device__ __forceinline__ float ftanh(float v) {
    v = fminf(fmaxf(v, -15.0f), 15.0f);
    const float e = __expf(2.0f * v);
    return (e - 1.0f) * fast_rcp(e + 1.0f);
}

// One WAVE per graph. Lane l = r*16+u owns gate row r (i,f,g,o) of hidden unit u.
// Per-lane weights: 18 (W_ih row) + 16 (W_hh row) + bias = 35 floats -> registers.
// Block = 256 threads = 4 graphs; grid = B/4 blocks -> 4 waves/SIMD occupancy.
extern "C" __global__ __launch_bounds__(256, 4)
void tgnn_lstm_fused(const float* __restrict__ x,
                     const float* __restrict__ W_ih,
                     const float* __restrict__ W_hh,
                     const float* __restrict__ b_ih,
                     const float* __restrict__ b_hh,
                     const float* __restrict__ W_fc,
                     const float* __restrict__ b_fc,
                     const int* __restrict__ edge_index,
                     const int* __restrict__ edge_attr,
                     const int* __restrict__ batch,
                     float* __restrict__ out,
                     int E, int B)
{
    __shared__ __align__(16) float feat[4][TSTEPS][20];  // padded rows (80B) -> bank-clean
    __shared__ __align__(16) float hbuf[4][HID];

    const int wave = threadIdx.x >> 6;
    const int wl   = threadIdx.x & 63;
    const int g    = blockIdx.x * 4 + wave;
    const int u    = wl & 15;          // hidden unit
    const int r    = wl >> 4;          // gate (0=i,1=f,2=g,3=o)

    // ---- weights into registers; loads issued first so latency overlaps search ----
    const int row = r * HID + u;
    float wih[FEAT], whh[HID];
#pragma unroll
    for (int k = 0; k < FEAT; ++k) wih[k] = W_ih[row * FEAT + k];
#pragma unroll
    for (int v = 0; v < HID; ++v) whh[v] = W_hh[row * HID + v];
    const float bias = b_ih[row] + b_hh[row];
    const float wfc  = W_fc[row];      // W_fc is [4][16]; out-row r, unit u
    const float bfc  = b_fc[r];

    // ---- dual interleaved 64-ary lower_bound: first=lb(g), end=lb(g+1) ----
    const int tgt1 = g, tgt2 = g + 1;
    int lo1 = 0, hi1 = E, lo2 = 0, hi2 = E;
    while ((hi1 - lo1) > 64 || (hi2 - lo2) > 64) {
        const unsigned n1 = (unsigned)(hi1 - lo1);
        const unsigned n2 = (unsigned)(hi2 - lo2);
        const int p1 = lo1 + (int)((n1 * (unsigned)wl) >> 6);   // < hi1 <= E
        const int p2 = lo2 + (int)((n2 * (unsigned)wl) >> 6);
        const int b1 = batch[p1];          // both probes in flight together
        const int b2 = batch[p2];
        const int c1 = __popcll(__ballot(b1 < tgt1));   // prefix property (sorted)
        const int c2 = __popcll(__ballot(b2 < tgt2));
        const int nlo1 = c1 ? (lo1 + (int)((n1 * (unsigned)(c1 - 1)) >> 6) + 1) : lo1;
        const int nhi1 = (c1 < 64) ? (lo1 + (int)((n1 * (unsigned)c1) >> 6)) : hi1;
        const int nlo2 = c2 ? (lo2 + (int)((n2 * (unsigned)(c2 - 1)) >> 6) + 1) : lo2;
        const int nhi2 = (c2 < 64) ? (lo2 + (int)((n2 * (unsigned)c2) >> 6)) : hi2;
        lo1 = nlo1; hi1 = nhi1; lo2 = nlo2; hi2 = nhi2;
    }
    {
        const int n1 = hi1 - lo1, n2 = hi2 - lo2;     // <= 64
        int p1 = lo1 + ((wl < n1) ? wl : 0);
        int p2 = lo2 + ((wl < n2) ? wl : 0);
        if (p1 > E - 1) p1 = E - 1;
        if (p2 > E - 1) p2 = E - 1;
        const int b1 = batch[p1];
        const int b2 = batch[p2];
        lo1 += __popcll(__ballot((wl < n1) && (b1 < tgt1)));
        lo2 += __popcll(__ballot((wl < n2) && (b2 < tgt2)));
    }
    const int first = lo1;
    int cnt = lo2 - first;
    cnt = (cnt < 0) ? 0 : ((cnt > TSTEPS) ? TSTEPS : cnt);

    // ---- gather round A: 54 lanes load src-id / dst-id / attr in ONE round ----
    const int side = (wl >= 36) ? 2 : ((wl >= 18) ? 1 : 0);
    const int te   = wl - side * 18;
    int j = first + te;
    if (j > E - 1) j = E - 1;
    int ev = 0;
    if (wl < 54) ev = (side == 2) ? edge_attr[j] : edge_index[side * E + j];
    // layout: lane t -> n1[t], lane 18+t -> n2[t], lane 36+t -> attr[t]

    // ---- gather round B: x sums + one-hot into LDS (lane-parallel) ----
    float* fb = &feat[wave][0][0];
#pragma unroll
    for (int i = 0; i < 4; ++i) {
        const unsigned s  = (unsigned)wl + 64u * (unsigned)i;   // slot (t,k), 198 used
        const unsigned t2 = s / 11u;
        const unsigned k2 = s - t2 * 11u;
        const int n1 = __shfl(ev, (int)t2, 64);        // garbage lanes still give valid node ids
        const int n2 = __shfl(ev, (int)t2 + 18, 64);
        const float xa = x[n1 * IN_SIZE + (int)k2];
        const float xb = x[n2 * IN_SIZE + (int)k2];
        if (s < 198u)
            fb[t2 * 20 + k2] = ((int)t2 < cnt) ? (xa + xb) : 0.0f;
    }
#pragma unroll
    for (int i = 0; i < 2; ++i) {
        const unsigned s  = (unsigned)wl + 64u * (unsigned)i;   // 126 one-hot slots
        const unsigned t2 = s / 7u;
        const unsigned k2 = s - t2 * 7u;
        const int at = __shfl(ev, (int)t2 + 36, 64);
        if (s < 126u)
            fb[t2 * 20 + 11 + k2] = (((int)t2 < cnt) && (at == (int)k2)) ? 1.0f : 0.0f;
    }

    // ---- LSTM: 34 FMAs/lane/step; gates exchanged by 4 shfl; h via LDS float4 ----
    if (r == 0) hbuf[wave][u] = 0.0f;
    float c = 0.0f, h = 0.0f;
    const float4* f4 = reinterpret_cast<const float4*>(fb);
    const float2* f2 = reinterpret_cast<const float2*>(fb);
    const float4* h4 = reinterpret_cast<const float4*>(hbuf[wave]);

    for (int t = 0; t < TSTEPS; ++t) {
        const float4 x0 = f4[t * 5 + 0];
        const float4 x1 = f4[t * 5 + 1];
        const float4 x2 = f4[t * 5 + 2];
        const float4 x3 = f4[t * 5 + 3];
        const float2 x4 = f2[t * 10 + 8];
        const float4 h0 = h4[0], h1 = h4[1], h2 = h4[2], h3 = h4[3];

        float a = bias;
        a = fmaf(x0.x, wih[0],  a); a = fmaf(x0.y, wih[1],  a);
        a = fmaf(x0.z, wih[2],  a); a = fmaf(x0.w, wih[3],  a);
        a = fmaf(x1.x, wih[4],  a); a = fmaf(x1.y, wih[5],  a);
        a = fmaf(x1.z, wih[6],  a); a = fmaf(x1.w, wih[7],  a);
        a = fmaf(x2.x, wih[8],  a); a = fmaf(x2.y, wih[9],  a);
        a = fmaf(x2.z, wih[10], a); a = fmaf(x2.w, wih[11], a);
        a = fmaf(x3.x, wih[12], a); a = fmaf(x3.y, wih[13], a);
        a = fmaf(x3.z, wih[14], a); a = fmaf(x3.w, wih[15], a);
        a = fmaf(x4.x, wih[16], a); a = fmaf(x4.y, wih[17], a);

        a = fmaf(h0.x, whh[0],  a); a = fmaf(h0.y, whh[1],  a);
        a = fmaf(h0.z, whh[2],  a); a = fmaf(h0.w, whh[3],  a);
        a = fmaf(h1.x, whh[4],  a); a = fmaf(h1.y, whh[5],  a);
        a = fmaf(h1.z, whh[6],  a); a = fmaf(h1.w, whh[7],  a);
        a = fmaf(h2.x, whh[8],  a); a = fmaf(h2.y, whh[9],  a);
        a = fmaf(h2.z, whh[10], a); a = fmaf(h2.w, whh[11], a);
        a = fmaf(h3.x, whh[12], a); a = fmaf(h3.y, whh[13], a);
        a = fmaf(h3.z, whh[14], a); a = fmaf(h3.w, whh[15], a);

        // exchange gate pre-activations: lane needs rows u, 16+u, 32+u, 48+u
        const float ai = __shfl(a, u,      64);
        const float af = __shfl(a, u + 16, 64);
        const float ag = __shfl(a, u + 32, 64);
        const float ao = __shfl(a, u + 48, 64);
        const float ig = fsigmoid(ai);
        const float fg = fsigmoid(af);
        const float gg = ftanh(ag);
        const float og = fsigmoid(ao);
        c = fmaf(fg, c, ig * gg);
        h = og * ftanh(c);
        if (r == 0) hbuf[wave][u] = h;   // broadcast h for next step
    }

    // ---- fc epilogue: out[g][r] = sum_u h[u]*W_fc[r][u] + b_fc[r] ----
    float p = h * wfc;
#pragma unroll
    for (int m = 8; m >= 1; m >>= 1) p += __shfl_xor(p, m, 16);
    if (u == 0 && g < B) out[g * 4 + r] = p + bfc;
}

extern "C" void kernel_launch(void* const* d_in, const int* in_sizes, int n_in,
                              void* d_out, int out_size, void* d_ws, size_t ws_size,
                              hipStream_t stream) {
    const float* x     = (const float*)d_in[0];
    const float* W_ih  = (const float*)d_in[1];
    const float* W_hh  = (const float*)d_in[2];
    const float* b_ih  = (const float*)d_in[3];
    const float* b_hh  = (const float*)d_in[4];
    const float* W_fc  = (const float*)d_in[5];
    const float* b_fc  = (const float*)d_in[6];
    const int* edge_index = (const int*)d_in[7];
    const int* edge_attr  = (const int*)d_in[8];
    const int* batch      = (const int*)d_in[9];

    const int E = in_sizes[8];       // N_EDGES
    const int B = out_size / 4;      // N_GRAPHS

    const int grid = (B + 3) / 4;    // 4 graphs (waves) per 256-thread block
    tgnn_lstm_fused<<<grid, 256, 0, stream>>>(x, W_ih, W_hh, b_ih, b_hh,
                                              W_fc, b_fc,
                                              edge_index, edge_attr, batch,
                                              (float*)d_out, E, B);
}